// Round 14
// baseline (180.035 us; speedup 1.0000x reference)
//
#include <hip/hip_runtime.h>

#define BS 256
#define THR 1024
#define EPB 8192          // edges per prep block (LDS-staged)
#define BSHC 6            // 64 nodes per coarse bucket
#define NPB 64            // nodes per bucket
#define CAPC 1536         // fixed capacity per bucket span (~1024 expected, 16-sigma margin)
#define AST 68            // fp32 LDS row stride (16B aligned, 2-way bank alias only)
#define SRC20 0x000FFFFF

typedef __attribute__((ext_vector_type(8))) short bf16x8;
typedef __attribute__((ext_vector_type(4))) float f32x4;

__device__ inline unsigned bfpack2(float a, float b) {
    unsigned ua = __float_as_uint(a), ub = __float_as_uint(b);
    ua = (ua + 0x7fffu + ((ua >> 16) & 1u)) >> 16;
    ub = (ub + 0x7fffu + ((ub >> 16) & 1u)) >> 16;
    return ua | (ub << 16);
}
__device__ inline float lo16(unsigned u) { return __uint_as_float(u << 16); }
__device__ inline float hi16(unsigned u) { return __uint_as_float(u & 0xffff0000u); }
__device__ inline bf16x8 pack8(float4 a, float4 b) {
    union { unsigned u[4]; bf16x8 v; } r;
    r.u[0] = bfpack2(a.x, a.y); r.u[1] = bfpack2(a.z, a.w);
    r.u[2] = bfpack2(b.x, b.y); r.u[3] = bfpack2(b.z, b.w);
    return r.v;
}

// ---------- ONE-PASS prep: ticketed bucket sort | x->bf16 | weight-frag pack ----------
__global__ __launch_bounds__(1024) void k_prep_all(const int* __restrict__ idx,
        int* __restrict__ curG, int* __restrict__ pk2, int E, int NBC, int nbs,
        const float* __restrict__ x, unsigned* __restrict__ xb, int total8,
        const float* __restrict__ W1l, const float* __restrict__ W1r,
        unsigned short* __restrict__ wfrag, int xblocks) {
    extern __shared__ int smem[];
    __shared__ int is64_s;
    int tid = threadIdx.x;
    int bid = blockIdx.x;

    if (bid < nbs) {
        int* pkL = smem;                                       // EPB ints
        unsigned short* binb = (unsigned short*)(smem + EPB);  // EPB ushorts
        int* hist  = (int*)(binb + EPB);                       // NBC
        int* gbase = hist + NBC;                               // NBC
        int* lcur  = gbase + NBC;                              // NBC
        for (int b = tid; b < NBC; b += THR) { hist[b] = 0; lcur[b] = 0; }
        if (tid < 64) {
            int v = idx[2 * tid + 1];
            unsigned long long bl = __ballot(v != 0);
            if (tid == 0) is64_s = (bl == 0ULL) ? 1 : 0;
        }
        __syncthreads();
        int is64 = is64_s;
        int base = bid * EPB;
        int ecnt = E - base; if (ecnt > EPB) ecnt = EPB;
#pragma unroll
        for (int j = 0; j < EPB / THR; j++) {
            int loc = j * THR + tid;
            if (loc < ecnt) {
                long e = base + loc;
                int s, d;
                if (is64) { s = idx[2 * e]; d = idx[2L * E + 2 * e]; }
                else      { s = idx[e];     d = idx[(long)E + e]; }
                pkL[loc] = s | ((d & (NPB - 1)) << 20);
                int bin = d >> BSHC;
                binb[loc] = (unsigned short)bin;
                atomicAdd(&hist[bin], 1);
            }
        }
        __syncthreads();
        for (int b = tid; b < NBC; b += THR) {
            int h = hist[b];
            gbase[b] = h ? atomicAdd(&curG[b * 16], h) : 0;
        }
        __syncthreads();
#pragma unroll
        for (int j = 0; j < EPB / THR; j++) {
            int loc = j * THR + tid;
            if (loc < ecnt) {
                int bin = binb[loc];
                int lpos = atomicAdd(&lcur[bin], 1);
                long gpos = (long)gbase[bin] + lpos;
                if (gpos < CAPC)              // overflow dropped; flagged via curG fill
                    pk2[(size_t)bin * CAPC + gpos] = pkL[loc];
            }
        }
    } else if (bid < nbs + xblocks) {
        int i = (bid - nbs) * THR + tid;
        if (i < total8) {
            const float4 a = *(const float4*)(x + (size_t)i * 8);
            const float4 b = *(const float4*)(x + (size_t)i * 8 + 4);
            uint4 o;
            o.x = bfpack2(a.x, a.y); o.y = bfpack2(a.z, a.w);
            o.z = bfpack2(b.x, b.y); o.w = bfpack2(b.z, b.w);
            *(uint4*)(xb + (size_t)i * 4) = o;
        }
    } else {
        if (tid < 64) {
            int lane = tid;
            int nloc = lane & 15, quad = lane >> 4;
            for (int p = 0; p < 2; p++) {
                const float* W = p ? W1r : W1l;
                for (int jt = 0; jt < 4; jt++) {
                    for (int ks = 0; ks < 2; ks++) {
                        float v[8];
#pragma unroll
                        for (int i = 0; i < 8; i++) {
                            int k = ks * 32 + quad * 8 + i;
                            v[i] = W[k * 64 + jt * 16 + nloc];
                        }
                        bf16x8 f = pack8(make_float4(v[0], v[1], v[2], v[3]),
                                         make_float4(v[4], v[5], v[6], v[7]));
                        int slot = (p * 4 + jt) * 2 + ks;
                        *(bf16x8*)(wfrag + ((size_t)slot * 64 + lane) * 8) = f;
                    }
                }
            }
        }
    }
}

// ---------- FUSED: 64-bin LDS sort + register-walk mean-agg + 4x4-tile MFMA ----------
// block = 1024 threads = one 64-node coarse bucket (4 MFMA node-tiles).
__global__ __launch_bounds__(1024) void k_agg_gemm(
        const unsigned short* __restrict__ xb, const int* __restrict__ pk2,
        const int* __restrict__ curG, const unsigned short* __restrict__ wfrag,
        const float* __restrict__ b1, const float* __restrict__ W2l,
        const float* __restrict__ W2r,
        float* __restrict__ sarr, float* __restrict__ tarr,
        float* __restrict__ invdeg, int n,
        const int* __restrict__ idx, int E) {
    __shared__ int ebuf[CAPC];
    __shared__ int srcb[CAPC];
    __shared__ int h64[NPB], base64[NPB], cur64[NPB];
    __shared__ float agg_s[NPB * AST];
    __shared__ float sred[4][NPB], tred[4][NPB];
    __shared__ int is64_s;

    int tid = threadIdx.x;
    int B = blockIdx.x;
    int grp = tid >> 4, l = tid & 15;          // grp = node-local 0..63
    int node = B * NPB + grp;
    int m = curG[B * 16];

    if (tid < NPB) { h64[tid] = 0; cur64[tid] = 0; }
    __syncthreads();

    float f0 = 0.f, f1 = 0.f, f2 = 0.f, f3 = 0.f;
    int cnt = 0;
    const unsigned short* xbase = xb + l * 4;
    size_t s0span = (size_t)B * CAPC;

    if (m <= CAPC) {
        for (int i = tid; i < m; i += THR) {
            int p = pk2[s0span + i];
            ebuf[i] = p;
            atomicAdd(&h64[(p >> 20) & (NPB - 1)], 1);
        }
        __syncthreads();
        if (tid == 0) {
            int run = 0;
#pragma unroll
            for (int q = 0; q < NPB; q++) { base64[q] = run; run += h64[q]; }
        }
        __syncthreads();
        for (int i = tid; i < m; i += THR) {
            int p = ebuf[i];
            int bin = (p >> 20) & (NPB - 1);
            int pos = base64[bin] + atomicAdd(&cur64[bin], 1);
            srcb[pos] = p & SRC20;
        }
        __syncthreads();
        cnt = h64[grp];
        int s0 = base64[grp];
        int e = 0;
        for (; e + 8 <= cnt; e += 8) {
            int j0 = srcb[s0+e+0], j1 = srcb[s0+e+1], j2 = srcb[s0+e+2], j3 = srcb[s0+e+3];
            int j4 = srcb[s0+e+4], j5 = srcb[s0+e+5], j6 = srcb[s0+e+6], j7 = srcb[s0+e+7];
            uint2 v0 = *(const uint2*)(xbase + (size_t)j0 * 64);
            uint2 v1 = *(const uint2*)(xbase + (size_t)j1 * 64);
            uint2 v2 = *(const uint2*)(xbase + (size_t)j2 * 64);
            uint2 v3 = *(const uint2*)(xbase + (size_t)j3 * 64);
            uint2 v4 = *(const uint2*)(xbase + (size_t)j4 * 64);
            uint2 v5 = *(const uint2*)(xbase + (size_t)j5 * 64);
            uint2 v6 = *(const uint2*)(xbase + (size_t)j6 * 64);
            uint2 v7 = *(const uint2*)(xbase + (size_t)j7 * 64);
            f0 += lo16(v0.x) + lo16(v1.x) + lo16(v2.x) + lo16(v3.x)
                + lo16(v4.x) + lo16(v5.x) + lo16(v6.x) + lo16(v7.x);
            f1 += hi16(v0.x) + hi16(v1.x) + hi16(v2.x) + hi16(v3.x)
                + hi16(v4.x) + hi16(v5.x) + hi16(v6.x) + hi16(v7.x);
            f2 += lo16(v0.y) + lo16(v1.y) + lo16(v2.y) + lo16(v3.y)
                + lo16(v4.y) + lo16(v5.y) + lo16(v6.y) + lo16(v7.y);
            f3 += hi16(v0.y) + hi16(v1.y) + hi16(v2.y) + hi16(v3.y)
                + hi16(v4.y) + hi16(v5.y) + hi16(v6.y) + hi16(v7.y);
        }
        for (; e < cnt; e++) {
            int j = srcb[s0 + e];
            uint2 v = *(const uint2*)(xbase + (size_t)j * 64);
            f0 += lo16(v.x); f1 += hi16(v.x); f2 += lo16(v.y); f3 += hi16(v.y);
        }
    } else {
        // flagged (span overflow, adversarial input): correct-but-slow direct idx scan
        if (tid < 64) {
            int v = idx[2 * tid + 1];
            unsigned long long bl = __ballot(v != 0);
            if (tid == 0) is64_s = (bl == 0ULL) ? 1 : 0;
        }
        __syncthreads();
        int is64 = is64_s;
        if (node < n) {
            for (long e = 0; e < E; e++) {
                int d = is64 ? idx[2L * E + 2 * e] : idx[(long)E + e];
                if (d == node) {
                    int s = is64 ? idx[2 * e] : idx[e];
                    cnt++;
                    uint2 v = *(const uint2*)(xbase + (size_t)s * 64);
                    f0 += lo16(v.x); f1 += hi16(v.x); f2 += lo16(v.y); f3 += hi16(v.y);
                }
            }
        }
    }
    {
        int d = cnt < 1 ? 1 : cnt;
        float inv = 1.0f / (float)d;
        f0 *= inv; f1 *= inv; f2 *= inv; f3 *= inv;
        if (l == 0 && node < n) invdeg[node] = inv;
    }
    *(float4*)(agg_s + grp * AST + l * 4) = make_float4(f0, f1, f2, f3);
    __syncthreads();

    // MFMA: wave w -> node-tile t = w&3, j-tile jt = w>>2  (16 waves cover 4x4)
    int wave = tid >> 6;
    int lane = tid & 63;
    int t = wave & 3, jt = wave >> 2;
    int nloc = lane & 15, quad = lane >> 4;

    const float* arow = agg_s + (t * 16 + nloc) * AST + quad * 8;
    bf16x8 aA0 = pack8(*(const float4*)(arow), *(const float4*)(arow + 4));
    bf16x8 aA1 = pack8(*(const float4*)(arow + 32), *(const float4*)(arow + 36));
    int node_a = B * NPB + t * 16 + nloc;
    int nc = node_a < n ? node_a : (n - 1);
    const unsigned short* xr = xb + (size_t)nc * 64;
    bf16x8 aX0 = *(const bf16x8*)(xr + quad * 8);
    bf16x8 aX1 = *(const bf16x8*)(xr + 32 + quad * 8);

    const bf16x8 bL0 = *(const bf16x8*)(wfrag + ((size_t)((0 * 4 + jt) * 2 + 0) * 64 + lane) * 8);
    const bf16x8 bL1 = *(const bf16x8*)(wfrag + ((size_t)((0 * 4 + jt) * 2 + 1) * 64 + lane) * 8);
    const bf16x8 bR0 = *(const bf16x8*)(wfrag + ((size_t)((1 * 4 + jt) * 2 + 0) * 64 + lane) * 8);
    const bf16x8 bR1 = *(const bf16x8*)(wfrag + ((size_t)((1 * 4 + jt) * 2 + 1) * 64 + lane) * 8);

    f32x4 acc = (f32x4){0.f, 0.f, 0.f, 0.f};
    acc = __builtin_amdgcn_mfma_f32_16x16x32_bf16(aA0, bL0, acc, 0, 0, 0);
    acc = __builtin_amdgcn_mfma_f32_16x16x32_bf16(aA1, bL1, acc, 0, 0, 0);
    acc = __builtin_amdgcn_mfma_f32_16x16x32_bf16(aX0, bR0, acc, 0, 0, 0);
    acc = __builtin_amdgcn_mfma_f32_16x16x32_bf16(aX1, bR1, acc, 0, 0, 0);

    int j = jt * 16 + nloc;
    float b1v = b1[j], w2lv = W2l[j], w2rv = W2r[j];
    float sp[4], tp[4];
#pragma unroll
    for (int r = 0; r < 4; r++) {
        float h = fmaxf(acc[r] + b1v, 0.f);
        sp[r] = h * w2lv;
        tp[r] = h * w2rv;
    }
#pragma unroll
    for (int mm = 1; mm < 16; mm <<= 1) {
#pragma unroll
        for (int r = 0; r < 4; r++) {
            sp[r] += __shfl_xor(sp[r], mm);
            tp[r] += __shfl_xor(tp[r], mm);
        }
    }
    if (nloc == 0) {
#pragma unroll
        for (int r = 0; r < 4; r++) {
            sred[jt][t * 16 + quad * 4 + r] = sp[r];
            tred[jt][t * 16 + quad * 4 + r] = tp[r];
        }
    }
    __syncthreads();
    if (tid < NPB) {
        int nd = B * NPB + tid;
        if (nd < n) {
            sarr[nd] = sred[0][tid] + sred[1][tid] + sred[2][tid] + sred[3][tid];
            tarr[nd] = tred[0][tid] + tred[1][tid] + tred[2][tid] + tred[3][tid];
        }
    }
}

// ---------- per-bucket layer-2 scalar mean-agg + output ----------
__global__ __launch_bounds__(1024) void k_final2(const int* __restrict__ pk2,
        const int* __restrict__ curG, const float* __restrict__ sarr,
        const float* __restrict__ tarr, const float* __restrict__ invdeg,
        const float* __restrict__ b2, float* __restrict__ out, int n,
        const int* __restrict__ idx, int E) {
    __shared__ float accr[NPB * 8];
    __shared__ int is64_s;
    int tid = threadIdx.x;
    int B = blockIdx.x;
    int m = curG[B * 16];
    if (tid < NPB * 8) accr[tid] = 0.f;
    __syncthreads();
    if (m <= CAPC) {
        size_t s0 = (size_t)B * CAPC;
        int rep = tid & 7;
        for (int i = tid; i < m; i += THR) {
            int p = pk2[s0 + i];
            float s = sarr[p & SRC20];
            atomicAdd(&accr[((p >> 20) & (NPB - 1)) * 8 + rep], s);
        }
        __syncthreads();
        if (tid < NPB) {
            int node = B * NPB + tid;
            if (node < n) {
                float a = 0.f;
#pragma unroll
                for (int r = 0; r < 8; r++) a += accr[tid * 8 + r];
                out[node] = a * invdeg[node] + b2[0] + tarr[node];
            }
        }
    } else {
        if (tid < 64) {
            int v = idx[2 * tid + 1];
            unsigned long long bl = __ballot(v != 0);
            if (tid == 0) is64_s = (bl == 0ULL) ? 1 : 0;
        }
        __syncthreads();
        int is64 = is64_s;
        if (tid < NPB) {
            int node = B * NPB + tid;
            if (node < n) {
                float a = 0.f;
                for (long e = 0; e < E; e++) {
                    int d = is64 ? idx[2L * E + 2 * e] : idx[(long)E + e];
                    if (d == node) {
                        int s = is64 ? idx[2 * e] : idx[e];
                        a += sarr[s];
                    }
                }
                out[node] = a * invdeg[node] + b2[0] + tarr[node];
            }
        }
    }
}

extern "C" void kernel_launch(void* const* d_in, const int* in_sizes, int n_in,
                              void* d_out, int out_size, void* d_ws, size_t ws_size,
                              hipStream_t stream) {
    const float* x   = (const float*)d_in[0];
    const int*   idx = (const int*)d_in[1];
    const float* W1l = (const float*)d_in[2];
    const float* b1  = (const float*)d_in[3];
    const float* W1r = (const float*)d_in[4];
    const float* W2l = (const float*)d_in[5];
    const float* b2  = (const float*)d_in[6];
    const float* W2r = (const float*)d_in[7];
    float* out = (float*)d_out;

    const int n = in_sizes[0] / 64;        // 100000
    const int E = in_sizes[1] / 2;         // 1600000
    const int NBC = (n + NPB - 1) >> BSHC; // 64-node buckets

    char* ws = (char*)d_ws;
    size_t off = 0;
    auto carve = [&](size_t bytes) {
        void* p = ws + off;
        off = (off + bytes + 255) & ~(size_t)255;
        return p;
    };
    float* sarr    = (float*)carve((size_t)n * 4);
    float* tarr    = (float*)carve((size_t)n * 4);
    float* invdeg  = (float*)carve((size_t)n * 4);
    int*   curG    = (int*)  carve((size_t)NBC * 64);   // 64B-padded cursors
    unsigned short* wfrag = (unsigned short*)carve(16 * 64 * 8 * 2);
    int*   pk2  = (int*)carve((size_t)NBC * CAPC * 4);
    unsigned short* xbu = (unsigned short*)carve((size_t)n * 128);
    (void)ws_size; (void)n_in; (void)out_size;

    const int total8 = n * 64 / 8;
    const int xblocks = (total8 + THR - 1) / THR;
    const int nbs = (E + EPB - 1) / EPB;
    const size_t dynLds = (size_t)EPB * 6 + (size_t)NBC * 12;

    hipMemsetAsync(curG, 0, (size_t)NBC * 64, stream);
    k_prep_all<<<nbs + xblocks + 1, THR, dynLds, stream>>>(
        idx, curG, pk2, E, NBC, nbs, x, (unsigned*)xbu, total8, W1l, W1r, wfrag, xblocks);
    k_agg_gemm<<<NBC, THR, 0, stream>>>(xbu, pk2, curG, wfrag, b1, W2l, W2r,
                                        sarr, tarr, invdeg, n, idx, E);
    k_final2<<<NBC, THR, 0, stream>>>(pk2, curG, sarr, tarr, invdeg, b2,
                                      out, n, idx, E);
}

// Round 15
// 172.279 us; speedup vs baseline: 1.0450x; 1.0450x over previous
//
#include <hip/hip_runtime.h>

#define BS 256
#define THR 1024
#define EPB 8192          // edges per prep block (LDS-sorted)
#define BSHC 8            // 256 nodes per COARSE bucket
#define CAPC 6144         // fixed capacity per coarse-bucket span (~4096 expected)
#define AST 68            // fp32 LDS row stride (16B aligned, 2-way bank alias only)
#define CAP 1024          // max edges per fine bucket for LDS sort (scan-filter beyond)
#define SRCMASK 0x0FFFFFFF
#define SRC20   0x000FFFFF

typedef __attribute__((ext_vector_type(8))) short bf16x8;
typedef __attribute__((ext_vector_type(4))) float f32x4;

__device__ inline unsigned bfpack2(float a, float b) {
    unsigned ua = __float_as_uint(a), ub = __float_as_uint(b);
    ua = (ua + 0x7fffu + ((ua >> 16) & 1u)) >> 16;
    ub = (ub + 0x7fffu + ((ub >> 16) & 1u)) >> 16;
    return ua | (ub << 16);
}
__device__ inline float lo16(unsigned u) { return __uint_as_float(u << 16); }
__device__ inline float hi16(unsigned u) { return __uint_as_float(u & 0xffff0000u); }
__device__ inline bf16x8 pack8(float4 a, float4 b) {
    union { unsigned u[4]; bf16x8 v; } r;
    r.u[0] = bfpack2(a.x, a.y); r.u[1] = bfpack2(a.z, a.w);
    r.u[2] = bfpack2(b.x, b.y); r.u[3] = bfpack2(b.z, b.w);
    return r.v;
}

// ---------- ONE-PASS prep: ticketed bucket sort | x->bf16 | weight-frag pack ----------
__global__ __launch_bounds__(1024) void k_prep_all(const int* __restrict__ idx,
        int* __restrict__ curG, int* __restrict__ pk2, int E, int NBC, int nbs,
        const float* __restrict__ x, unsigned* __restrict__ xb, int total8,
        const float* __restrict__ W1l, const float* __restrict__ W1r,
        unsigned short* __restrict__ wfrag, int xblocks) {
    extern __shared__ int smem[];
    __shared__ int is64_s;
    int tid = threadIdx.x;
    int bid = blockIdx.x;

    if (bid < nbs) {
        int* pkL = smem;                                   // EPB ints
        unsigned short* binb = (unsigned short*)(smem + EPB);  // EPB ushorts
        int* hist  = (int*)(binb + EPB);                   // NBC
        int* gbase = hist + NBC;                           // NBC
        int* lcur  = gbase + NBC;                          // NBC
        for (int b = tid; b < NBC; b += THR) { hist[b] = 0; lcur[b] = 0; }
        if (tid < 64) {
            int v = idx[2 * tid + 1];
            unsigned long long bl = __ballot(v != 0);
            if (tid == 0) is64_s = (bl == 0ULL) ? 1 : 0;
        }
        __syncthreads();
        int is64 = is64_s;
        int base = bid * EPB;
        int ecnt = E - base; if (ecnt > EPB) ecnt = EPB;
#pragma unroll
        for (int j = 0; j < EPB / THR; j++) {
            int loc = j * THR + tid;
            if (loc < ecnt) {
                long e = base + loc;
                int s, d;
                if (is64) { s = idx[2 * e]; d = idx[2L * E + 2 * e]; }
                else      { s = idx[e];     d = idx[(long)E + e]; }
                pkL[loc] = s | ((d & 255) << 20);
                int bin = d >> BSHC;
                binb[loc] = (unsigned short)bin;
                atomicAdd(&hist[bin], 1);
            }
        }
        __syncthreads();
        for (int b = tid; b < NBC; b += THR) {
            int h = hist[b];
            gbase[b] = h ? atomicAdd(&curG[b * 16], h) : 0;
        }
        __syncthreads();
#pragma unroll
        for (int j = 0; j < EPB / THR; j++) {
            int loc = j * THR + tid;
            if (loc < ecnt) {
                int bin = binb[loc];
                int lpos = atomicAdd(&lcur[bin], 1);
                long gpos = (long)gbase[bin] + lpos;
                if (gpos < CAPC)             // overflow edges dropped; bucket flagged via curG
                    pk2[(size_t)bin * CAPC + gpos] = pkL[loc];
            }
        }
    } else if (bid < nbs + xblocks) {
        int i = (bid - nbs) * THR + tid;
        if (i < total8) {
            const float4 a = *(const float4*)(x + (size_t)i * 8);
            const float4 b = *(const float4*)(x + (size_t)i * 8 + 4);
            uint4 o;
            o.x = bfpack2(a.x, a.y); o.y = bfpack2(a.z, a.w);
            o.z = bfpack2(b.x, b.y); o.w = bfpack2(b.z, b.w);
            *(uint4*)(xb + (size_t)i * 4) = o;
        }
    } else {
        if (tid < 64) {
            int lane = tid;
            int nloc = lane & 15, quad = lane >> 4;
            for (int p = 0; p < 2; p++) {
                const float* W = p ? W1r : W1l;
                for (int jt = 0; jt < 4; jt++) {
                    for (int ks = 0; ks < 2; ks++) {
                        float v[8];
#pragma unroll
                        for (int i = 0; i < 8; i++) {
                            int k = ks * 32 + quad * 8 + i;
                            v[i] = W[k * 64 + jt * 16 + nloc];
                        }
                        bf16x8 f = pack8(make_float4(v[0], v[1], v[2], v[3]),
                                         make_float4(v[4], v[5], v[6], v[7]));
                        int slot = (p * 4 + jt) * 2 + ks;
                        *(bf16x8*)(wfrag + ((size_t)slot * 64 + lane) * 8) = f;
                    }
                }
            }
        }
    }
}

// ---------- refine: coarse span -> 16 fine buckets in place-adjacent span ----------
__global__ __launch_bounds__(1024) void k_refine(const int* __restrict__ pk2,
        const int* __restrict__ curG, int* __restrict__ fstart, int* __restrict__ fcnt,
        int* __restrict__ pk3, int NBC) {
    __shared__ int h16f[16], base16f[16], cur16f[16];
    int tid = threadIdx.x;
    int B = blockIdx.x;
    int fill = curG[B * 16];
    if (fill > CAPC) {           // overflow (adversarial input): flag for slow path
        if (tid < 16) fcnt[B * 16 + tid] = -1;
        return;
    }
    if (tid < 16) { h16f[tid] = 0; cur16f[tid] = 0; }
    __syncthreads();
    size_t s0 = (size_t)B * CAPC;
    for (int i = tid; i < fill; i += THR)
        atomicAdd(&h16f[(pk2[s0 + i] >> 24) & 15], 1);
    __syncthreads();
    if (tid == 0) {
        int run = 0;
#pragma unroll
        for (int f = 0; f < 16; f++) { base16f[f] = run; run += h16f[f]; }
    }
    __syncthreads();
    if (tid < 16) {
        fstart[B * 16 + tid] = (int)(s0 + base16f[tid]);
        fcnt[B * 16 + tid] = h16f[tid];
    }
    for (int i = tid; i < fill; i += THR) {
        int p = pk2[s0 + i];
        int f = (p >> 24) & 15;
        int pos = atomicAdd(&cur16f[f], 1);
        pk3[s0 + base16f[f] + pos] = (p & SRC20) | (((p >> 20) & 15) << 28);
    }
}

// ---------- FUSED: LDS counting-sort + register-walk mean-agg + MFMA + epilogue ----------
__global__ __launch_bounds__(256) void k_agg_gemm(
        const unsigned short* __restrict__ xb, const int* __restrict__ pk3,
        const int* __restrict__ fstart, const int* __restrict__ fcnt,
        const unsigned short* __restrict__ wfrag,
        const float* __restrict__ b1, const float* __restrict__ W2l,
        const float* __restrict__ W2r,
        float* __restrict__ sarr, float* __restrict__ tarr,
        float* __restrict__ invdeg, int n,
        const int* __restrict__ idx, int E) {
    __shared__ int ebuf[CAP];
    __shared__ int srcb[CAP];
    __shared__ int h16[16], base16[16], cur16[16];
    __shared__ float agg_s[16 * AST];
    __shared__ float sred[4 * 16], tred[4 * 16];
    __shared__ int is64_s;

    int tid = threadIdx.x;
    int b = blockIdx.x;
    int grp = tid >> 4, l = tid & 15;
    int node = b * 16 + grp;
    int m = fcnt[b];

    if (tid < 16) { h16[tid] = 0; cur16[tid] = 0; }
    __syncthreads();

    float f0 = 0.f, f1 = 0.f, f2 = 0.f, f3 = 0.f;
    int cnt = 0;
    const unsigned short* xbase = xb + l * 4;

    if (m >= 0 && m <= CAP) {
        int ebeg = fstart[b];
        for (int i = tid; i < m; i += 256) {
            int p = pk3[ebeg + i];
            ebuf[i] = p;
            atomicAdd(&h16[((unsigned)p) >> 28], 1);
        }
        __syncthreads();
        if (tid == 0) {
            int run = 0;
#pragma unroll
            for (int j = 0; j < 16; j++) { base16[j] = run; run += h16[j]; }
        }
        __syncthreads();
        for (int i = tid; i < m; i += 256) {
            int p = ebuf[i];
            int bin = ((unsigned)p) >> 28;
            int pos = base16[bin] + atomicAdd(&cur16[bin], 1);
            srcb[pos] = p & SRCMASK;
        }
        __syncthreads();
        cnt = h16[grp];
        int s0 = base16[grp];
        int e = 0;
        for (; e + 16 <= cnt; e += 16) {
            uint2 v[16];
#pragma unroll
            for (int q = 0; q < 16; q++)
                v[q] = *(const uint2*)(xbase + (size_t)srcb[s0 + e + q] * 64);
#pragma unroll
            for (int q = 0; q < 16; q++) {
                f0 += lo16(v[q].x); f1 += hi16(v[q].x);
                f2 += lo16(v[q].y); f3 += hi16(v[q].y);
            }
        }
        for (; e + 8 <= cnt; e += 8) {
            uint2 v[8];
#pragma unroll
            for (int q = 0; q < 8; q++)
                v[q] = *(const uint2*)(xbase + (size_t)srcb[s0 + e + q] * 64);
#pragma unroll
            for (int q = 0; q < 8; q++) {
                f0 += lo16(v[q].x); f1 += hi16(v[q].x);
                f2 += lo16(v[q].y); f3 += hi16(v[q].y);
            }
        }
        for (; e < cnt; e++) {
            int j = srcb[s0 + e];
            uint2 v = *(const uint2*)(xbase + (size_t)j * 64);
            f0 += lo16(v.x); f1 += hi16(v.x); f2 += lo16(v.y); f3 += hi16(v.y);
        }
    } else if (m > CAP) {
        // scan-filter within the (fine-sorted) span
        int ebeg = fstart[b];
        for (int i = 0; i < m; i++) {
            int p = pk3[ebeg + i];
            if ((int)(((unsigned)p) >> 28) == grp) {
                cnt++;
                uint2 v = *(const uint2*)(xbase + (size_t)(p & SRCMASK) * 64);
                f0 += lo16(v.x); f1 += hi16(v.x); f2 += lo16(v.y); f3 += hi16(v.y);
            }
        }
    } else {
        // flagged (span overflow): correct-but-slow direct scan of idx
        if (tid < 64) {
            int v = idx[2 * tid + 1];
            unsigned long long bl = __ballot(v != 0);
            if (tid == 0) is64_s = (bl == 0ULL) ? 1 : 0;
        }
        __syncthreads();
        int is64 = is64_s;
        if (node < n) {
            for (long e = 0; e < E; e++) {
                int d = is64 ? idx[2L * E + 2 * e] : idx[(long)E + e];
                if (d == node) {
                    int s = is64 ? idx[2 * e] : idx[e];
                    cnt++;
                    uint2 v = *(const uint2*)(xbase + (size_t)s * 64);
                    f0 += lo16(v.x); f1 += hi16(v.x); f2 += lo16(v.y); f3 += hi16(v.y);
                }
            }
        }
    }
    {
        int d = cnt < 1 ? 1 : cnt;
        float inv = 1.0f / (float)d;
        f0 *= inv; f1 *= inv; f2 *= inv; f3 *= inv;
        if (l == 0 && node < n) invdeg[node] = inv;
    }
    *(float4*)(agg_s + grp * AST + l * 4) = make_float4(f0, f1, f2, f3);
    __syncthreads();

    int wave = tid >> 6;
    int lane = tid & 63;
    int nloc = lane & 15, quad = lane >> 4;

    const float* arow = agg_s + nloc * AST + quad * 8;
    bf16x8 aA0 = pack8(*(const float4*)(arow), *(const float4*)(arow + 4));
    bf16x8 aA1 = pack8(*(const float4*)(arow + 32), *(const float4*)(arow + 36));
    int node_a = b * 16 + nloc;
    int nc = node_a < n ? node_a : (n - 1);
    const unsigned short* xr = xb + (size_t)nc * 64;
    bf16x8 aX0 = *(const bf16x8*)(xr + quad * 8);
    bf16x8 aX1 = *(const bf16x8*)(xr + 32 + quad * 8);

    const bf16x8 bL0 = *(const bf16x8*)(wfrag + ((size_t)((0 * 4 + wave) * 2 + 0) * 64 + lane) * 8);
    const bf16x8 bL1 = *(const bf16x8*)(wfrag + ((size_t)((0 * 4 + wave) * 2 + 1) * 64 + lane) * 8);
    const bf16x8 bR0 = *(const bf16x8*)(wfrag + ((size_t)((1 * 4 + wave) * 2 + 0) * 64 + lane) * 8);
    const bf16x8 bR1 = *(const bf16x8*)(wfrag + ((size_t)((1 * 4 + wave) * 2 + 1) * 64 + lane) * 8);

    f32x4 acc = (f32x4){0.f, 0.f, 0.f, 0.f};
    acc = __builtin_amdgcn_mfma_f32_16x16x32_bf16(aA0, bL0, acc, 0, 0, 0);
    acc = __builtin_amdgcn_mfma_f32_16x16x32_bf16(aA1, bL1, acc, 0, 0, 0);
    acc = __builtin_amdgcn_mfma_f32_16x16x32_bf16(aX0, bR0, acc, 0, 0, 0);
    acc = __builtin_amdgcn_mfma_f32_16x16x32_bf16(aX1, bR1, acc, 0, 0, 0);

    int j = wave * 16 + nloc;
    float b1v = b1[j], w2lv = W2l[j], w2rv = W2r[j];
    float sp[4], tp[4];
#pragma unroll
    for (int r = 0; r < 4; r++) {
        float h = fmaxf(acc[r] + b1v, 0.f);
        sp[r] = h * w2lv;
        tp[r] = h * w2rv;
    }
#pragma unroll
    for (int mm = 1; mm < 16; mm <<= 1) {
#pragma unroll
        for (int r = 0; r < 4; r++) {
            sp[r] += __shfl_xor(sp[r], mm);
            tp[r] += __shfl_xor(tp[r], mm);
        }
    }
    if (nloc == 0) {
#pragma unroll
        for (int r = 0; r < 4; r++) {
            sred[wave * 16 + quad * 4 + r] = sp[r];
            tred[wave * 16 + quad * 4 + r] = tp[r];
        }
    }
    __syncthreads();
    if (tid < 16) {
        int nd = b * 16 + tid;
        if (nd < n) {
            sarr[nd] = sred[tid] + sred[16 + tid] + sred[32 + tid] + sred[48 + tid];
            tarr[nd] = tred[tid] + tred[16 + tid] + tred[32 + tid] + tred[48 + tid];
        }
    }
}

// ---------- per-fine-bucket layer-2 mean aggregation + output ----------
__global__ __launch_bounds__(256) void k_final2(const int* __restrict__ pk3,
        const int* __restrict__ fstart, const int* __restrict__ fcnt,
        const float* __restrict__ sarr, const float* __restrict__ tarr,
        const float* __restrict__ invdeg, const float* __restrict__ b2,
        float* __restrict__ out, int n,
        const int* __restrict__ idx, int E) {
    __shared__ float accr[16 * 8];
    __shared__ int is64_s;
    int tid = threadIdx.x;
    int b = blockIdx.x;
    int m = fcnt[b];
    if (tid < 128) accr[tid] = 0.f;
    __syncthreads();
    if (m >= 0) {
        int ebeg = fstart[b];
        int rep = tid & 7;
        for (int i = ebeg + tid; i < ebeg + m; i += 256) {
            int p = pk3[i];
            float s = sarr[p & SRCMASK];
            atomicAdd(&accr[(((unsigned)p) >> 28) * 8 + rep], s);
        }
        __syncthreads();
        if (tid < 16) {
            int node = b * 16 + tid;
            if (node < n) {
                float a = 0.f;
#pragma unroll
                for (int r = 0; r < 8; r++) a += accr[tid * 8 + r];
                out[node] = a * invdeg[node] + b2[0] + tarr[node];
            }
        }
    } else {
        // flagged: slow direct scan
        if (tid < 64) {
            int v = idx[2 * tid + 1];
            unsigned long long bl = __ballot(v != 0);
            if (tid == 0) is64_s = (bl == 0ULL) ? 1 : 0;
        }
        __syncthreads();
        int is64 = is64_s;
        if (tid < 16) {
            int node = b * 16 + tid;
            if (node < n) {
                float a = 0.f;
                for (long e = 0; e < E; e++) {
                    int d = is64 ? idx[2L * E + 2 * e] : idx[(long)E + e];
                    if (d == node) {
                        int s = is64 ? idx[2 * e] : idx[e];
                        a += sarr[s];
                    }
                }
                out[node] = a * invdeg[node] + b2[0] + tarr[node];
            }
        }
    }
}

extern "C" void kernel_launch(void* const* d_in, const int* in_sizes, int n_in,
                              void* d_out, int out_size, void* d_ws, size_t ws_size,
                              hipStream_t stream) {
    const float* x   = (const float*)d_in[0];
    const int*   idx = (const int*)d_in[1];
    const float* W1l = (const float*)d_in[2];
    const float* b1  = (const float*)d_in[3];
    const float* W1r = (const float*)d_in[4];
    const float* W2l = (const float*)d_in[5];
    const float* b2  = (const float*)d_in[6];
    const float* W2r = (const float*)d_in[7];
    float* out = (float*)d_out;

    const int n = in_sizes[0] / 64;       // 100000
    const int E = in_sizes[1] / 2;        // 1600000
    const int NBC = (n + 255) >> BSHC;    // coarse buckets (256 nodes)
    const int NBF = NBC * 16;             // fine buckets (16 nodes)

    char* ws = (char*)d_ws;
    size_t off = 0;
    auto carve = [&](size_t bytes) {
        void* p = ws + off;
        off = (off + bytes + 255) & ~(size_t)255;
        return p;
    };
    float* sarr    = (float*)carve((size_t)n * 4);
    float* tarr    = (float*)carve((size_t)n * 4);
    float* invdeg  = (float*)carve((size_t)n * 4);
    int*   curG    = (int*)  carve((size_t)NBC * 64);        // 64B-padded cursors
    int*   fstart  = (int*)  carve((size_t)NBF * 4);
    int*   fcnt    = (int*)  carve((size_t)NBF * 4);
    unsigned short* wfrag = (unsigned short*)carve(16 * 64 * 8 * 2);
    int*   pk2  = (int*)carve((size_t)NBC * CAPC * 4);
    int*   pk3  = (int*)carve((size_t)NBC * CAPC * 4);
    unsigned short* xbu = (unsigned short*)carve((size_t)n * 128);
    (void)ws_size; (void)n_in; (void)out_size;

    const int total8 = n * 64 / 8;
    const int xblocks = (total8 + THR - 1) / THR;
    const int nbs = (E + EPB - 1) / EPB;
    const size_t dynLds = (size_t)EPB * 6 + (size_t)NBC * 12;

    hipMemsetAsync(curG, 0, (size_t)NBC * 64, stream);
    k_prep_all<<<nbs + xblocks + 1, THR, dynLds, stream>>>(
        idx, curG, pk2, E, NBC, nbs, x, (unsigned*)xbu, total8, W1l, W1r, wfrag, xblocks);
    k_refine<<<NBC, THR, 0, stream>>>(pk2, curG, fstart, fcnt, pk3, NBC);
    k_agg_gemm<<<NBF, BS, 0, stream>>>(xbu, pk3, fstart, fcnt, wfrag, b1, W2l, W2r,
                                       sarr, tarr, invdeg, n, idx, E);
    k_final2<<<NBF, BS, 0, stream>>>(pk3, fstart, fcnt, sarr, tarr, invdeg, b2,
                                     out, n, idx, E);
}

// Round 16
// 163.044 us; speedup vs baseline: 1.1042x; 1.0566x over previous
//
#include <hip/hip_runtime.h>

#define BS 256
#define THR 1024
#define EPB 8192          // edges per prep block (LDS-sorted)
#define BSHC 8            // 256 nodes per COARSE bucket
#define CAPC 6144         // fixed capacity per coarse-bucket span (~4096 expected, 32-sigma margin)
#define AST 68            // fp32 LDS row stride (16B aligned, 2-way bank alias only)
#define CAP 1024          // max edges per fine bucket for LDS sort (scan-filter beyond)
#define SRCMASK 0x0FFFFFFF
#define SRC20   0x000FFFFF

typedef __attribute__((ext_vector_type(8))) short bf16x8;
typedef __attribute__((ext_vector_type(4))) float f32x4;

__device__ inline unsigned bfpack2(float a, float b) {
    unsigned ua = __float_as_uint(a), ub = __float_as_uint(b);
    ua = (ua + 0x7fffu + ((ua >> 16) & 1u)) >> 16;
    ub = (ub + 0x7fffu + ((ub >> 16) & 1u)) >> 16;
    return ua | (ub << 16);
}
__device__ inline float lo16(unsigned u) { return __uint_as_float(u << 16); }
__device__ inline float hi16(unsigned u) { return __uint_as_float(u & 0xffff0000u); }
__device__ inline bf16x8 pack8(float4 a, float4 b) {
    union { unsigned u[4]; bf16x8 v; } r;
    r.u[0] = bfpack2(a.x, a.y); r.u[1] = bfpack2(a.z, a.w);
    r.u[2] = bfpack2(b.x, b.y); r.u[3] = bfpack2(b.z, b.w);
    return r.v;
}

// ---------- ONE-PASS prep: ticketed bucket sort | x->bf16 | weight-frag pack ----------
// Edge section: LDS-buffer 8192 edges, 391-bin hist, ONE global atomic per (block,bin)
// reserving a contiguous run in the bucket's fixed-capacity span, then line-local writes.
__global__ __launch_bounds__(1024) void k_prep_all(const int* __restrict__ idx,
        int* __restrict__ curG, int* __restrict__ pk2, int E, int NBC, int nbs,
        const float* __restrict__ x, unsigned* __restrict__ xb, int total8,
        const float* __restrict__ W1l, const float* __restrict__ W1r,
        unsigned short* __restrict__ wfrag, int xblocks) {
    extern __shared__ int smem[];
    __shared__ int is64_s;
    int tid = threadIdx.x;
    int bid = blockIdx.x;

    if (bid < nbs) {
        int* pkL = smem;                                   // EPB ints
        unsigned short* binb = (unsigned short*)(smem + EPB);  // EPB ushorts
        int* hist  = (int*)(binb + EPB);                   // NBC
        int* gbase = hist + NBC;                           // NBC
        int* lcur  = gbase + NBC;                          // NBC
        for (int b = tid; b < NBC; b += THR) { hist[b] = 0; lcur[b] = 0; }
        if (tid < 64) {
            int v = idx[2 * tid + 1];
            unsigned long long bl = __ballot(v != 0);
            if (tid == 0) is64_s = (bl == 0ULL) ? 1 : 0;
        }
        __syncthreads();
        int is64 = is64_s;
        int base = bid * EPB;
        int ecnt = E - base; if (ecnt > EPB) ecnt = EPB;
#pragma unroll
        for (int j = 0; j < EPB / THR; j++) {
            int loc = j * THR + tid;
            if (loc < ecnt) {
                long e = base + loc;
                int s, d;
                if (is64) { s = idx[2 * e]; d = idx[2L * E + 2 * e]; }
                else      { s = idx[e];     d = idx[(long)E + e]; }
                pkL[loc] = s | ((d & 255) << 20);
                int bin = d >> BSHC;
                binb[loc] = (unsigned short)bin;
                atomicAdd(&hist[bin], 1);
            }
        }
        __syncthreads();
        for (int b = tid; b < NBC; b += THR) {
            int h = hist[b];
            gbase[b] = h ? atomicAdd(&curG[b * 16], h) : 0;
        }
        __syncthreads();
#pragma unroll
        for (int j = 0; j < EPB / THR; j++) {
            int loc = j * THR + tid;
            if (loc < ecnt) {
                int bin = binb[loc];
                int lpos = atomicAdd(&lcur[bin], 1);
                long gpos = (long)gbase[bin] + lpos;
                if (gpos < CAPC)             // overflow edges dropped; bucket flagged via curG
                    pk2[(size_t)bin * CAPC + gpos] = pkL[loc];
            }
        }
    } else if (bid < nbs + xblocks) {
        int i = (bid - nbs) * THR + tid;
        if (i < total8) {
            const float4 a = *(const float4*)(x + (size_t)i * 8);
            const float4 b = *(const float4*)(x + (size_t)i * 8 + 4);
            uint4 o;
            o.x = bfpack2(a.x, a.y); o.y = bfpack2(a.z, a.w);
            o.z = bfpack2(b.x, b.y); o.w = bfpack2(b.z, b.w);
            *(uint4*)(xb + (size_t)i * 4) = o;
        }
    } else {
        if (tid < 64) {
            int lane = tid;
            int nloc = lane & 15, quad = lane >> 4;
            for (int p = 0; p < 2; p++) {
                const float* W = p ? W1r : W1l;
                for (int jt = 0; jt < 4; jt++) {
                    for (int ks = 0; ks < 2; ks++) {
                        float v[8];
#pragma unroll
                        for (int i = 0; i < 8; i++) {
                            int k = ks * 32 + quad * 8 + i;
                            v[i] = W[k * 64 + jt * 16 + nloc];
                        }
                        bf16x8 f = pack8(make_float4(v[0], v[1], v[2], v[3]),
                                         make_float4(v[4], v[5], v[6], v[7]));
                        int slot = (p * 4 + jt) * 2 + ks;
                        *(bf16x8*)(wfrag + ((size_t)slot * 64 + lane) * 8) = f;
                    }
                }
            }
        }
    }
}

// ---------- refine: coarse span -> 16 fine buckets in place-adjacent span ----------
__global__ __launch_bounds__(1024) void k_refine(const int* __restrict__ pk2,
        const int* __restrict__ curG, int* __restrict__ fstart, int* __restrict__ fcnt,
        int* __restrict__ pk3, int NBC) {
    __shared__ int h16f[16], base16f[16], cur16f[16];
    int tid = threadIdx.x;
    int B = blockIdx.x;
    int fill = curG[B * 16];
    if (fill > CAPC) {           // overflow (adversarial input): flag for slow path
        if (tid < 16) fcnt[B * 16 + tid] = -1;
        return;
    }
    if (tid < 16) { h16f[tid] = 0; cur16f[tid] = 0; }
    __syncthreads();
    size_t s0 = (size_t)B * CAPC;
    for (int i = tid; i < fill; i += THR)
        atomicAdd(&h16f[(pk2[s0 + i] >> 24) & 15], 1);
    __syncthreads();
    if (tid == 0) {
        int run = 0;
#pragma unroll
        for (int f = 0; f < 16; f++) { base16f[f] = run; run += h16f[f]; }
    }
    __syncthreads();
    if (tid < 16) {
        fstart[B * 16 + tid] = (int)(s0 + base16f[tid]);
        fcnt[B * 16 + tid] = h16f[tid];
    }
    for (int i = tid; i < fill; i += THR) {
        int p = pk2[s0 + i];
        int f = (p >> 24) & 15;
        int pos = atomicAdd(&cur16f[f], 1);
        pk3[s0 + base16f[f] + pos] = (p & SRC20) | (((p >> 20) & 15) << 28);
    }
}

// ---------- FUSED: LDS counting-sort + register-walk mean-agg + MFMA + epilogue ----------
__global__ __launch_bounds__(256) void k_agg_gemm(
        const unsigned short* __restrict__ xb, const int* __restrict__ pk3,
        const int* __restrict__ fstart, const int* __restrict__ fcnt,
        const unsigned short* __restrict__ wfrag,
        const float* __restrict__ b1, const float* __restrict__ W2l,
        const float* __restrict__ W2r,
        float* __restrict__ sarr, float* __restrict__ tarr,
        float* __restrict__ invdeg, int n,
        const int* __restrict__ idx, int E) {
    __shared__ int ebuf[CAP];
    __shared__ int srcb[CAP];
    __shared__ int h16[16], base16[16], cur16[16];
    __shared__ float agg_s[16 * AST];
    __shared__ float sred[4 * 16], tred[4 * 16];
    __shared__ int is64_s;

    int tid = threadIdx.x;
    int b = blockIdx.x;
    int grp = tid >> 4, l = tid & 15;
    int node = b * 16 + grp;
    int m = fcnt[b];

    if (tid < 16) { h16[tid] = 0; cur16[tid] = 0; }
    __syncthreads();

    float f0 = 0.f, f1 = 0.f, f2 = 0.f, f3 = 0.f;
    int cnt = 0;
    const unsigned short* xbase = xb + l * 4;

    if (m >= 0 && m <= CAP) {
        int ebeg = fstart[b];
        for (int i = tid; i < m; i += 256) {
            int p = pk3[ebeg + i];
            ebuf[i] = p;
            atomicAdd(&h16[((unsigned)p) >> 28], 1);
        }
        __syncthreads();
        if (tid == 0) {
            int run = 0;
#pragma unroll
            for (int j = 0; j < 16; j++) { base16[j] = run; run += h16[j]; }
        }
        __syncthreads();
        for (int i = tid; i < m; i += 256) {
            int p = ebuf[i];
            int bin = ((unsigned)p) >> 28;
            int pos = base16[bin] + atomicAdd(&cur16[bin], 1);
            srcb[pos] = p & SRCMASK;
        }
        __syncthreads();
        cnt = h16[grp];
        int s0 = base16[grp];
        int e = 0;
        for (; e + 8 <= cnt; e += 8) {
            int j0 = srcb[s0+e+0], j1 = srcb[s0+e+1], j2 = srcb[s0+e+2], j3 = srcb[s0+e+3];
            int j4 = srcb[s0+e+4], j5 = srcb[s0+e+5], j6 = srcb[s0+e+6], j7 = srcb[s0+e+7];
            uint2 v0 = *(const uint2*)(xbase + (size_t)j0 * 64);
            uint2 v1 = *(const uint2*)(xbase + (size_t)j1 * 64);
            uint2 v2 = *(const uint2*)(xbase + (size_t)j2 * 64);
            uint2 v3 = *(const uint2*)(xbase + (size_t)j3 * 64);
            uint2 v4 = *(const uint2*)(xbase + (size_t)j4 * 64);
            uint2 v5 = *(const uint2*)(xbase + (size_t)j5 * 64);
            uint2 v6 = *(const uint2*)(xbase + (size_t)j6 * 64);
            uint2 v7 = *(const uint2*)(xbase + (size_t)j7 * 64);
            f0 += lo16(v0.x) + lo16(v1.x) + lo16(v2.x) + lo16(v3.x)
                + lo16(v4.x) + lo16(v5.x) + lo16(v6.x) + lo16(v7.x);
            f1 += hi16(v0.x) + hi16(v1.x) + hi16(v2.x) + hi16(v3.x)
                + hi16(v4.x) + hi16(v5.x) + hi16(v6.x) + hi16(v7.x);
            f2 += lo16(v0.y) + lo16(v1.y) + lo16(v2.y) + lo16(v3.y)
                + lo16(v4.y) + lo16(v5.y) + lo16(v6.y) + lo16(v7.y);
            f3 += hi16(v0.y) + hi16(v1.y) + hi16(v2.y) + hi16(v3.y)
                + hi16(v4.y) + hi16(v5.y) + hi16(v6.y) + hi16(v7.y);
        }
        for (; e < cnt; e++) {
            int j = srcb[s0 + e];
            uint2 v = *(const uint2*)(xbase + (size_t)j * 64);
            f0 += lo16(v.x); f1 += hi16(v.x); f2 += lo16(v.y); f3 += hi16(v.y);
        }
    } else if (m > CAP) {
        // scan-filter within the (fine-sorted) span
        int ebeg = fstart[b];
        for (int i = 0; i < m; i++) {
            int p = pk3[ebeg + i];
            if ((int)(((unsigned)p) >> 28) == grp) {
                cnt++;
                uint2 v = *(const uint2*)(xbase + (size_t)(p & SRCMASK) * 64);
                f0 += lo16(v.x); f1 += hi16(v.x); f2 += lo16(v.y); f3 += hi16(v.y);
            }
        }
    } else {
        // flagged (span overflow): correct-but-slow direct scan of idx
        if (tid < 64) {
            int v = idx[2 * tid + 1];
            unsigned long long bl = __ballot(v != 0);
            if (tid == 0) is64_s = (bl == 0ULL) ? 1 : 0;
        }
        __syncthreads();
        int is64 = is64_s;
        if (node < n) {
            for (long e = 0; e < E; e++) {
                int d = is64 ? idx[2L * E + 2 * e] : idx[(long)E + e];
                if (d == node) {
                    int s = is64 ? idx[2 * e] : idx[e];
                    cnt++;
                    uint2 v = *(const uint2*)(xbase + (size_t)s * 64);
                    f0 += lo16(v.x); f1 += hi16(v.x); f2 += lo16(v.y); f3 += hi16(v.y);
                }
            }
        }
    }
    {
        int d = cnt < 1 ? 1 : cnt;
        float inv = 1.0f / (float)d;
        f0 *= inv; f1 *= inv; f2 *= inv; f3 *= inv;
        if (l == 0 && node < n) invdeg[node] = inv;
    }
    *(float4*)(agg_s + grp * AST + l * 4) = make_float4(f0, f1, f2, f3);
    __syncthreads();

    int wave = tid >> 6;
    int lane = tid & 63;
    int nloc = lane & 15, quad = lane >> 4;

    const float* arow = agg_s + nloc * AST + quad * 8;
    bf16x8 aA0 = pack8(*(const float4*)(arow), *(const float4*)(arow + 4));
    bf16x8 aA1 = pack8(*(const float4*)(arow + 32), *(const float4*)(arow + 36));
    int node_a = b * 16 + nloc;
    int nc = node_a < n ? node_a : (n - 1);
    const unsigned short* xr = xb + (size_t)nc * 64;
    bf16x8 aX0 = *(const bf16x8*)(xr + quad * 8);
    bf16x8 aX1 = *(const bf16x8*)(xr + 32 + quad * 8);

    const bf16x8 bL0 = *(const bf16x8*)(wfrag + ((size_t)((0 * 4 + wave) * 2 + 0) * 64 + lane) * 8);
    const bf16x8 bL1 = *(const bf16x8*)(wfrag + ((size_t)((0 * 4 + wave) * 2 + 1) * 64 + lane) * 8);
    const bf16x8 bR0 = *(const bf16x8*)(wfrag + ((size_t)((1 * 4 + wave) * 2 + 0) * 64 + lane) * 8);
    const bf16x8 bR1 = *(const bf16x8*)(wfrag + ((size_t)((1 * 4 + wave) * 2 + 1) * 64 + lane) * 8);

    f32x4 acc = (f32x4){0.f, 0.f, 0.f, 0.f};
    acc = __builtin_amdgcn_mfma_f32_16x16x32_bf16(aA0, bL0, acc, 0, 0, 0);
    acc = __builtin_amdgcn_mfma_f32_16x16x32_bf16(aA1, bL1, acc, 0, 0, 0);
    acc = __builtin_amdgcn_mfma_f32_16x16x32_bf16(aX0, bR0, acc, 0, 0, 0);
    acc = __builtin_amdgcn_mfma_f32_16x16x32_bf16(aX1, bR1, acc, 0, 0, 0);

    int j = wave * 16 + nloc;
    float b1v = b1[j], w2lv = W2l[j], w2rv = W2r[j];
    float sp[4], tp[4];
#pragma unroll
    for (int r = 0; r < 4; r++) {
        float h = fmaxf(acc[r] + b1v, 0.f);
        sp[r] = h * w2lv;
        tp[r] = h * w2rv;
    }
#pragma unroll
    for (int mm = 1; mm < 16; mm <<= 1) {
#pragma unroll
        for (int r = 0; r < 4; r++) {
            sp[r] += __shfl_xor(sp[r], mm);
            tp[r] += __shfl_xor(tp[r], mm);
        }
    }
    if (nloc == 0) {
#pragma unroll
        for (int r = 0; r < 4; r++) {
            sred[wave * 16 + quad * 4 + r] = sp[r];
            tred[wave * 16 + quad * 4 + r] = tp[r];
        }
    }
    __syncthreads();
    if (tid < 16) {
        int nd = b * 16 + tid;
        if (nd < n) {
            sarr[nd] = sred[tid] + sred[16 + tid] + sred[32 + tid] + sred[48 + tid];
            tarr[nd] = tred[tid] + tred[16 + tid] + tred[32 + tid] + tred[48 + tid];
        }
    }
}

// ---------- per-fine-bucket layer-2 mean aggregation + output ----------
__global__ __launch_bounds__(256) void k_final2(const int* __restrict__ pk3,
        const int* __restrict__ fstart, const int* __restrict__ fcnt,
        const float* __restrict__ sarr, const float* __restrict__ tarr,
        const float* __restrict__ invdeg, const float* __restrict__ b2,
        float* __restrict__ out, int n,
        const int* __restrict__ idx, int E) {
    __shared__ float accr[16 * 8];
    __shared__ int is64_s;
    int tid = threadIdx.x;
    int b = blockIdx.x;
    int m = fcnt[b];
    if (tid < 128) accr[tid] = 0.f;
    __syncthreads();
    if (m >= 0) {
        int ebeg = fstart[b];
        int rep = tid & 7;
        for (int i = ebeg + tid; i < ebeg + m; i += 256) {
            int p = pk3[i];
            float s = sarr[p & SRCMASK];
            atomicAdd(&accr[(((unsigned)p) >> 28) * 8 + rep], s);
        }
        __syncthreads();
        if (tid < 16) {
            int node = b * 16 + tid;
            if (node < n) {
                float a = 0.f;
#pragma unroll
                for (int r = 0; r < 8; r++) a += accr[tid * 8 + r];
                out[node] = a * invdeg[node] + b2[0] + tarr[node];
            }
        }
    } else {
        // flagged: slow direct scan
        if (tid < 64) {
            int v = idx[2 * tid + 1];
            unsigned long long bl = __ballot(v != 0);
            if (tid == 0) is64_s = (bl == 0ULL) ? 1 : 0;
        }
        __syncthreads();
        int is64 = is64_s;
        if (tid < 16) {
            int node = b * 16 + tid;
            if (node < n) {
                float a = 0.f;
                for (long e = 0; e < E; e++) {
                    int d = is64 ? idx[2L * E + 2 * e] : idx[(long)E + e];
                    if (d == node) {
                        int s = is64 ? idx[2 * e] : idx[e];
                        a += sarr[s];
                    }
                }
                out[node] = a * invdeg[node] + b2[0] + tarr[node];
            }
        }
    }
}

extern "C" void kernel_launch(void* const* d_in, const int* in_sizes, int n_in,
                              void* d_out, int out_size, void* d_ws, size_t ws_size,
                              hipStream_t stream) {
    const float* x   = (const float*)d_in[0];
    const int*   idx = (const int*)d_in[1];
    const float* W1l = (const float*)d_in[2];
    const float* b1  = (const float*)d_in[3];
    const float* W1r = (const float*)d_in[4];
    const float* W2l = (const float*)d_in[5];
    const float* b2  = (const float*)d_in[6];
    const float* W2r = (const float*)d_in[7];
    float* out = (float*)d_out;

    const int n = in_sizes[0] / 64;       // 100000
    const int E = in_sizes[1] / 2;        // 1600000
    const int NBC = (n + 255) >> BSHC;    // coarse buckets (256 nodes)
    const int NBF = NBC * 16;             // fine buckets (16 nodes)

    char* ws = (char*)d_ws;
    size_t off = 0;
    auto carve = [&](size_t bytes) {
        void* p = ws + off;
        off = (off + bytes + 255) & ~(size_t)255;
        return p;
    };
    float* sarr    = (float*)carve((size_t)n * 4);
    float* tarr    = (float*)carve((size_t)n * 4);
    float* invdeg  = (float*)carve((size_t)n * 4);
    int*   curG    = (int*)  carve((size_t)NBC * 64);        // 64B-padded cursors
    int*   fstart  = (int*)  carve((size_t)NBF * 4);
    int*   fcnt    = (int*)  carve((size_t)NBF * 4);
    unsigned short* wfrag = (unsigned short*)carve(16 * 64 * 8 * 2);
    int*   pk2  = (int*)carve((size_t)NBC * CAPC * 4);
    int*   pk3  = (int*)carve((size_t)NBC * CAPC * 4);
    unsigned short* xbu = (unsigned short*)carve((size_t)n * 128);
    (void)ws_size; (void)n_in; (void)out_size;

    const int total8 = n * 64 / 8;
    const int xblocks = (total8 + THR - 1) / THR;
    const int nbs = (E + EPB - 1) / EPB;
    const size_t dynLds = (size_t)EPB * 6 + (size_t)NBC * 12;

    hipMemsetAsync(curG, 0, (size_t)NBC * 64, stream);
    k_prep_all<<<nbs + xblocks + 1, THR, dynLds, stream>>>(
        idx, curG, pk2, E, NBC, nbs, x, (unsigned*)xbu, total8, W1l, W1r, wfrag, xblocks);
    k_refine<<<NBC, THR, 0, stream>>>(pk2, curG, fstart, fcnt, pk3, NBC);
    k_agg_gemm<<<NBF, BS, 0, stream>>>(xbu, pk3, fstart, fcnt, wfrag, b1, W2l, W2r,
                                       sarr, tarr, invdeg, n, idx, E);
    k_final2<<<NBF, BS, 0, stream>>>(pk3, fstart, fcnt, sarr, tarr, invdeg, b2,
                                     out, n, idx, E);
}